// Round 5
// baseline (286.932 us; speedup 1.0000x reference)
//
#include <hip/hip_runtime.h>

// GlobalFilter: y = irfft2(rfft2(x, ortho) * W, ortho)  ==  per-channel 14x14
// circular convolution with kernel R_c = (1/196) * Re(IFFT2(Wext_c)).
//
// x: (256, 196, 512) fp32, W: (14, 8, 512, 2) fp32, out: (256, 196, 512) fp32.
//
// ws layout: R  at offset 0            : 196*512 floats  (401,408 B)
//               *** pair layout ***: R[((dm*7 + dn/2)*512 + c)*2 + (dn&1)]
//            T  at offset 196*512      : 14*14*512*2 floats (802,816 B)  [complex]
//
// Round-5 (= round-4 resubmit after infra failure): the whole per-p inner
// computation lives in ONE inline-asm block with hard-clobbered temp VGPRs
// (v40..v81), so the register allocator cannot demote operands to LDS
// re-reads (the failure mode of rounds 0-3: VGPR_Count 36-52, 2.3x VALU
// overhead, VALUBusy pinned at ~55%).

#define Hs 14
#define Ns 196          // 14*14
#define Cc 512
#define CT 32           // channel tile
#define CONV_THREADS 448

typedef float v2f __attribute__((ext_vector_type(2)));

// ---------------------------------------------------------------------------
// Prep stage A (unchanged)
// ---------------------------------------------------------------------------
__global__ __launch_bounds__(256) void prep_a_kernel(const float* __restrict__ cw,
                                                     float* __restrict__ T) {
    __shared__ float cs[14], sn[14];
    if (threadIdx.x < 14) {
        float ang = (float)threadIdx.x * 0.44879895051282760549f;  // 2*pi/14
        cs[threadIdx.x] = cosf(ang);
        sn[threadIdx.x] = sinf(ang);
    }
    __syncthreads();

    int gid = blockIdx.x * 256 + threadIdx.x;   // 14*14*512
    int c = gid & 511;
    int s = gid >> 9;          // h*14 + dn
    int h = s / 14;
    int dn = s % 14;
    int h2 = (h == 0) ? 0 : (14 - h);

    float Tr = 0.0f, Ti = 0.0f;
    int k = 0;
    #pragma unroll
    for (int w = 0; w < 8; ++w) {
        const float* p = cw + (size_t)(((h * 8 + w) * 512 + c) * 2);
        float Wr = p[0], Wi = p[1];
        Tr += Wr * cs[k] - Wi * sn[k];
        Ti += Wr * sn[k] + Wi * cs[k];
        k += dn; if (k >= 14) k -= 14;
    }
    int k2 = dn; if (k2 >= 14) k2 -= 14;
    #pragma unroll
    for (int w = 1; w < 7; ++w) {
        const float* p = cw + (size_t)(((h2 * 8 + w) * 512 + c) * 2);
        float Wr = p[0], Wi = p[1];
        Tr += Wr * cs[k2] - Wi * sn[k2];
        Ti -= Wr * sn[k2] + Wi * cs[k2];
        k2 += dn; if (k2 >= 14) k2 -= 14;
    }
    float* o = T + (size_t)(s * 512 + c) * 2;
    o[0] = Tr;
    o[1] = Ti;
}

// ---------------------------------------------------------------------------
// Prep stage B (unchanged; writes R in dn-PAIR layout)
// ---------------------------------------------------------------------------
__global__ __launch_bounds__(256) void prep_b_kernel(const float* __restrict__ T,
                                                     float* __restrict__ R) {
    __shared__ float cs[14], sn[14];
    if (threadIdx.x < 14) {
        float ang = (float)threadIdx.x * 0.44879895051282760549f;  // 2*pi/14
        cs[threadIdx.x] = cosf(ang);
        sn[threadIdx.x] = sinf(ang);
    }
    __syncthreads();

    int gid = blockIdx.x * 256 + threadIdx.x;   // 196*512
    int c = gid & 511;
    int s = gid >> 9;          // dm*14 + dn
    int dm = s / 14;
    int dn = s % 14;

    float acc = 0.0f;
    int kh = 0;
    #pragma unroll
    for (int h = 0; h < 14; ++h) {
        const float* p = T + (size_t)(((h * 14 + dn) * 512 + c) * 2);
        acc += p[0] * cs[kh] - p[1] * sn[kh];
        kh += dm; if (kh >= 14) kh -= 14;
    }
    R[(size_t)(((dm * 7 + (dn >> 1)) * 512 + c) * 2 + (dn & 1))] = acc * (1.0f / 196.0f);
}

// ---------------------------------------------------------------------------
// Conv kernel.  Per p, one asm block:
//   14x ds_read_b64 -> v[40..67]  (x row p, this thread's column c; both
//                                  half-waves read identical addrs = broadcast)
//    7x ds_read_b64 -> v[68..81]  (R pairs, row dm)
//   s_waitcnt lgkmcnt(0)
//   196x v_pk_fma_f32, diagonal-major: for dn, acc[(q+dn)%14] += x[q]*r[dn],
//   r half selected via op_sel (even->lo, odd->hi; verified round 2).
// LDS is c-major with padded strides (199 / 99 v2f) for ~2-way bank aliasing.
// ---------------------------------------------------------------------------
#define SEL_E "op_sel:[0,0,0] op_sel_hi:[1,0,1]"
#define SEL_O "op_sel:[0,1,0] op_sel_hi:[1,1,1]"

#define DIAG(R, S, a0,a1,a2,a3,a4,a5,a6,a7,a8,a9,aA,aB,aC,aD) \
  "v_pk_fma_f32 %" #a0 ", v[40:41], " R ", %" #a0 " " S "\n\t" \
  "v_pk_fma_f32 %" #a1 ", v[42:43], " R ", %" #a1 " " S "\n\t" \
  "v_pk_fma_f32 %" #a2 ", v[44:45], " R ", %" #a2 " " S "\n\t" \
  "v_pk_fma_f32 %" #a3 ", v[46:47], " R ", %" #a3 " " S "\n\t" \
  "v_pk_fma_f32 %" #a4 ", v[48:49], " R ", %" #a4 " " S "\n\t" \
  "v_pk_fma_f32 %" #a5 ", v[50:51], " R ", %" #a5 " " S "\n\t" \
  "v_pk_fma_f32 %" #a6 ", v[52:53], " R ", %" #a6 " " S "\n\t" \
  "v_pk_fma_f32 %" #a7 ", v[54:55], " R ", %" #a7 " " S "\n\t" \
  "v_pk_fma_f32 %" #a8 ", v[56:57], " R ", %" #a8 " " S "\n\t" \
  "v_pk_fma_f32 %" #a9 ", v[58:59], " R ", %" #a9 " " S "\n\t" \
  "v_pk_fma_f32 %" #aA ", v[60:61], " R ", %" #aA " " S "\n\t" \
  "v_pk_fma_f32 %" #aB ", v[62:63], " R ", %" #aB " " S "\n\t" \
  "v_pk_fma_f32 %" #aC ", v[64:65], " R ", %" #aC " " S "\n\t" \
  "v_pk_fma_f32 %" #aD ", v[66:67], " R ", %" #aD " " S "\n\t"

#define XSTRIDE 199   // v2f units, c-major row stride for xs (396+2 dwords)
#define RSTRIDE 99    // v2f units, c-major row stride for rs

__global__ __launch_bounds__(CONV_THREADS, 2) void conv_kernel(
        const float* __restrict__ x,
        const float* __restrict__ R,
        float* __restrict__ out) {
    __shared__ v2f xs[CT * XSTRIDE];    // 50,944 B  (c-major, batch-paired x)
    __shared__ v2f rs[CT * RSTRIDE];    // 25,344 B  (c-major, dn-paired R)

    const int bx = blockIdx.x;          // 2048 blocks
    const int ct = bx & 15;             // 16 channel tiles of 32
    const int bp = bx >> 4;             // 0..127 batch pairs
    const int c0 = ct * CT;
    const int b0 = bp * 2;
    const int t  = threadIdx.x;

    const float* xb = x + (size_t)b0 * Ns * Cc + c0;
    const v2f*  Rbv = (const v2f*)R + c0;          // pair units, channel offset
    for (int i = t; i < Ns * CT; i += CONV_THREADS) {
        int pq = i >> 5;
        int cc = i & (CT - 1);
        v2f v;
        v.x = xb[pq * Cc + cc];
        v.y = xb[(size_t)Ns * Cc + pq * Cc + cc];
        xs[cc * XSTRIDE + pq] = v;
    }
    for (int i = t; i < 98 * CT; i += CONV_THREADS) {
        int j  = i >> 5;
        int cc = i & (CT - 1);
        rs[cc * RSTRIDE + j] = Rbv[j * Cc + cc];
    }
    __syncthreads();

    const int c = t & (CT - 1);
    const int m = t >> 5;               // 0..13

    v2f acc[14];
    #pragma unroll
    for (int n = 0; n < 14; ++n) acc[n] = 0.0f;

    // 32-bit LDS byte addresses (low 32 bits of generic pointer = LDS offset)
    const unsigned xs_c = (unsigned)(size_t)&xs[c * XSTRIDE];
    const unsigned rs_c = (unsigned)(size_t)&rs[c * RSTRIDE];

    int dm = m;
    #pragma unroll 1
    for (int p = 0; p < 14; ++p) {
        unsigned xa = xs_c + (unsigned)(p * 14 * 8);   // row p of x (14 v2f)
        unsigned ra = rs_c + (unsigned)(dm * 7 * 8);   // row dm of R (7 pairs)
        asm volatile(
            "ds_read_b64 v[40:41], %14\n\t"
            "ds_read_b64 v[42:43], %14 offset:8\n\t"
            "ds_read_b64 v[44:45], %14 offset:16\n\t"
            "ds_read_b64 v[46:47], %14 offset:24\n\t"
            "ds_read_b64 v[48:49], %14 offset:32\n\t"
            "ds_read_b64 v[50:51], %14 offset:40\n\t"
            "ds_read_b64 v[52:53], %14 offset:48\n\t"
            "ds_read_b64 v[54:55], %14 offset:56\n\t"
            "ds_read_b64 v[56:57], %14 offset:64\n\t"
            "ds_read_b64 v[58:59], %14 offset:72\n\t"
            "ds_read_b64 v[60:61], %14 offset:80\n\t"
            "ds_read_b64 v[62:63], %14 offset:88\n\t"
            "ds_read_b64 v[64:65], %14 offset:96\n\t"
            "ds_read_b64 v[66:67], %14 offset:104\n\t"
            "ds_read_b64 v[68:69], %15\n\t"
            "ds_read_b64 v[70:71], %15 offset:8\n\t"
            "ds_read_b64 v[72:73], %15 offset:16\n\t"
            "ds_read_b64 v[74:75], %15 offset:24\n\t"
            "ds_read_b64 v[76:77], %15 offset:32\n\t"
            "ds_read_b64 v[78:79], %15 offset:40\n\t"
            "ds_read_b64 v[80:81], %15 offset:48\n\t"
            "s_waitcnt lgkmcnt(0)\n\t"
            DIAG("v[68:69]", SEL_E,  0,1,2,3,4,5,6,7,8,9,10,11,12,13)
            DIAG("v[68:69]", SEL_O,  1,2,3,4,5,6,7,8,9,10,11,12,13,0)
            DIAG("v[70:71]", SEL_E,  2,3,4,5,6,7,8,9,10,11,12,13,0,1)
            DIAG("v[70:71]", SEL_O,  3,4,5,6,7,8,9,10,11,12,13,0,1,2)
            DIAG("v[72:73]", SEL_E,  4,5,6,7,8,9,10,11,12,13,0,1,2,3)
            DIAG("v[72:73]", SEL_O,  5,6,7,8,9,10,11,12,13,0,1,2,3,4)
            DIAG("v[74:75]", SEL_E,  6,7,8,9,10,11,12,13,0,1,2,3,4,5)
            DIAG("v[74:75]", SEL_O,  7,8,9,10,11,12,13,0,1,2,3,4,5,6)
            DIAG("v[76:77]", SEL_E,  8,9,10,11,12,13,0,1,2,3,4,5,6,7)
            DIAG("v[76:77]", SEL_O,  9,10,11,12,13,0,1,2,3,4,5,6,7,8)
            DIAG("v[78:79]", SEL_E,  10,11,12,13,0,1,2,3,4,5,6,7,8,9)
            DIAG("v[78:79]", SEL_O,  11,12,13,0,1,2,3,4,5,6,7,8,9,10)
            DIAG("v[80:81]", SEL_E,  12,13,0,1,2,3,4,5,6,7,8,9,10,11)
            DIAG("v[80:81]", SEL_O,  13,0,1,2,3,4,5,6,7,8,9,10,11,12)
            : "+v"(acc[0]), "+v"(acc[1]), "+v"(acc[2]), "+v"(acc[3]),
              "+v"(acc[4]), "+v"(acc[5]), "+v"(acc[6]), "+v"(acc[7]),
              "+v"(acc[8]), "+v"(acc[9]), "+v"(acc[10]), "+v"(acc[11]),
              "+v"(acc[12]), "+v"(acc[13])
            : "v"(xa), "v"(ra)
            : "memory",
              "v40","v41","v42","v43","v44","v45","v46","v47",
              "v48","v49","v50","v51","v52","v53","v54","v55",
              "v56","v57","v58","v59","v60","v61","v62","v63",
              "v64","v65","v66","v67","v68","v69","v70","v71",
              "v72","v73","v74","v75","v76","v77","v78","v79",
              "v80","v81");
        dm = (dm == 0) ? 13 : (dm - 1);
    }

    float* o0 = out + ((size_t)b0 * Ns + m * 14) * Cc + c0 + c;
    float* o1 = o0 + (size_t)Ns * Cc;
    #pragma unroll
    for (int n = 0; n < 14; ++n) {
        o0[n * Cc] = acc[n].x;
        o1[n * Cc] = acc[n].y;
    }
}

extern "C" void kernel_launch(void* const* d_in, const int* in_sizes, int n_in,
                              void* d_out, int out_size, void* d_ws, size_t ws_size,
                              hipStream_t stream) {
    const float* x  = (const float*)d_in[0];
    const float* cw = (const float*)d_in[1];
    float* outp = (float*)d_out;
    float* R = (float*)d_ws;                    // 196*512 floats (pair layout)
    float* T = R + (size_t)Ns * Cc;             // 14*14*512*2 floats

    prep_a_kernel<<<392, 256, 0, stream>>>(cw, T);
    prep_b_kernel<<<392, 256, 0, stream>>>(T, R);
    conv_kernel<<<128 * 16, CONV_THREADS, 0, stream>>>(x, R, outp);
}